// Round 4
// baseline (45.248 us; speedup 1.0000x reference)
//
#include <hip/hip_runtime.h>

#define IH 224
#define IW 224
#define PH 55
#define PW 55

__device__ __forceinline__ float4 max4(float4 a, float4 b) {
  return make_float4(fmaxf(a.x, b.x), fmaxf(a.y, b.y),
                     fmaxf(a.z, b.z), fmaxf(a.w, b.w));
}

// Two blocks per (b, c): half 0 -> pooled rows 0..27 (groups 0..28),
// half 1 -> pooled rows 28..54 (groups 28..55).  Each thread loads ONE
// float4 per row (4 rows), computes the 4x4 chunk max, and gets the
// neighboring chunk via __shfl_down -> each input byte issued exactly once.
__global__ __launch_bounds__(256) void pool_minmax_kernel(
    const float* __restrict__ x,
    float* __restrict__ partmin,    // [1536]
    float* __restrict__ partmax,    // [1536]
    float* __restrict__ poolv)      // [256 * 165]
{
  __shared__ float gm[29 * 64];     // per-group horizontal window maxes
  __shared__ float rmin[4], rmax[4];

  const int blk  = blockIdx.x;
  const int bc   = blk >> 1;        // b*3 + c
  const int half = blk & 1;
  const int b    = bc / 3;
  const int c    = bc - b * 3;
  const int t    = threadIdx.x;

  const int g0  = half ? 28 : 0;    // first row-group of this half
  const int ng  = half ? 28 : 29;   // groups in this half
  const int nph = half ? 27 : 28;   // pooled rows in this half

  const float* img = x + (size_t)bc * (IH * IW);
  const float NEG = -3.4e38f;

  // stage 1: gm[g][wp] = max over rows 4g..4g+3, cols 4wp..4wp+7
  const int ncell = ng * 64;
  #pragma unroll 2
  for (int i = t; i < ncell; i += 256) {
    const int g  = g0 + (i >> 6);
    const int wp = i & 63;          // chunk index (chunks valid < 56)
    float cm = NEG;
    if (wp < 56) {
      const float* p0 = img + (4 * g) * IW + 4 * wp;
      float4 a0 = *reinterpret_cast<const float4*>(p0);
      float4 a1 = *reinterpret_cast<const float4*>(p0 + IW);
      float4 a2 = *reinterpret_cast<const float4*>(p0 + 2 * IW);
      float4 a3 = *reinterpret_cast<const float4*>(p0 + 3 * IW);
      float4 mm = max4(max4(a0, a1), max4(a2, a3));
      cm = fmaxf(fmaxf(mm.x, mm.y), fmaxf(mm.z, mm.w));
    }
    const float nb = __shfl_down(cm, 1);   // neighbor chunk (wp+1)
    gm[i] = fmaxf(cm, nb);                 // valid for wp < 55
  }
  __syncthreads();

  // stage 2: pooled[p][w] = max(gm[p], gm[p+1]) (relative rows); min/max
  float lmin = 3.4e38f, lmax = NEG;
  const int npc = nph * 64;
  for (int i = t; i < npc; i += 256) {
    const int hp = i >> 6;          // pooled row relative to this half
    const int w  = i & 63;
    if (w < PW) {
      float pm = fmaxf(gm[i], gm[i + 64]);
      lmin = fminf(lmin, pm);
      lmax = fmaxf(lmax, pm);
      if (c == 0 && half == 0 && hp < 3) poolv[b * 165 + hp * 55 + w] = pm;
    }
  }

  for (int off = 32; off > 0; off >>= 1) {
    lmin = fminf(lmin, __shfl_down(lmin, off));
    lmax = fmaxf(lmax, __shfl_down(lmax, off));
  }
  if ((t & 63) == 0) { rmin[t >> 6] = lmin; rmax[t >> 6] = lmax; }
  __syncthreads();
  if (t == 0) {
    partmin[blk] = fminf(fminf(rmin[0], rmin[1]), fminf(rmin[2], rmin[3]));
    partmax[blk] = fmaxf(fmaxf(rmax[0], rmax[1]), fmaxf(rmax[2], rmax[3]));
  }
}

// One block per batch. Threads 0..63 compute the 64 hash positions into LDS;
// then all 256 threads write the full 8192-float output row (zeros + ones).
__global__ __launch_bounds__(256) void encode_kernel(
    const int* __restrict__ R,
    const float* __restrict__ partmin,
    const float* __restrict__ partmax,
    const float* __restrict__ poolv,
    float* __restrict__ out)
{
  __shared__ int sp[64];
  const int b = blockIdx.x;
  const int t = threadIdx.x;

  float xmin = partmin[b * 6], xmax = partmax[b * 6];
  #pragma unroll
  for (int i = 1; i < 6; ++i) {
    xmin = fminf(xmin, partmin[b * 6 + i]);
    xmax = fmaxf(xmax, partmax[b * 6 + i]);
  }
  const float denom = xmax - xmin + 1e-8f;   // same op order as reference

  if (t < 64) {
    int p = 0;
    #pragma unroll
    for (int k = 0; k < 8; ++k) {
      int idx = R[t * 8 + k] % 72600;        // n_elements = 3*55*55*8
      int f   = idx >> 3;                    // feature index (< 125 given R<1000)
      int l   = idx & 7;                     // threshold level
      float xn = (poolv[b * 165 + f] - xmin) / denom;
      if (xn > (float)(l + 1) * 0.125f) p += 128 >> k;   // weights 2^(7-k)
    }
    sp[t] = p & 127;                         // % VECTOR_SIZE (128)
  }
  __syncthreads();

  float* orow = out + (size_t)b * 8192;
  #pragma unroll
  for (int j = 0; j < 8; ++j) {
    const int e  = (j * 256 + t) * 4;        // element base (4 floats/thread)
    const int m  = e >> 7;                   // which of the 64 vectors
    const int q  = e & 127;                  // position within vector
    const int pm = sp[m];
    float4 v = make_float4(0.f, 0.f, 0.f, 0.f);
    const int d = pm - q;
    if (d >= 0 && d < 4) ((float*)&v)[d] = 1.0f;
    *reinterpret_cast<float4*>(orow + e) = v;
  }
}

extern "C" void kernel_launch(void* const* d_in, const int* in_sizes, int n_in,
                              void* d_out, int out_size, void* d_ws, size_t ws_size,
                              hipStream_t stream) {
  const float* x   = (const float*)d_in[0];
  const int*   R   = (const int*)d_in[1];
  float*       out = (float*)d_out;

  float* partmin = (float*)d_ws;             // [1536]
  float* partmax = partmin + 1536;           // [1536]
  float* poolv   = partmax + 1536;           // [256 * 165]

  pool_minmax_kernel<<<1536, 256, 0, stream>>>(x, partmin, partmax, poolv);
  encode_kernel<<<256, 256, 0, stream>>>(R, partmin, partmax, poolv, out);
}

// Round 5
// 32.915 us; speedup vs baseline: 1.3747x; 1.3747x over previous
//
#include <hip/hip_runtime.h>

#define IH 224
#define IW 224
#define PH 55
#define PW 55
#define NBLK 1536          // 2 blocks per (b,c)
#define OUT_FLOATS (256 * 8192)

__device__ __forceinline__ float4 max4(float4 a, float4 b) {
  return make_float4(fmaxf(a.x, b.x), fmaxf(a.y, b.y),
                     fmaxf(a.z, b.z), fmaxf(a.w, b.w));
}

// Two blocks per (b, c): half 0 -> pooled rows 0..27 (groups 0..28),
// half 1 -> pooled rows 28..54 (groups 28..55).  Also zeros its grid-stride
// slice of d_out up front (stores overlap the streaming reads).
__global__ __launch_bounds__(256) void pool_minmax_kernel(
    const float* __restrict__ x,
    float* __restrict__ partmin,    // [1536]
    float* __restrict__ partmax,    // [1536]
    float* __restrict__ poolv,      // [256 * 165]
    float* __restrict__ out)        // [256 * 8192] zeroed here
{
  __shared__ float gm[29 * 64];     // per-group horizontal window maxes
  __shared__ float rmin[4], rmax[4];

  const int blk  = blockIdx.x;
  const int bc   = blk >> 1;        // b*3 + c
  const int half = blk & 1;
  const int b    = bc / 3;
  const int c    = bc - b * 3;
  const int t    = threadIdx.x;

  // ---- zero d_out slice (fire-and-forget stores, overlap with reads) ----
  {
    const float4 z = make_float4(0.f, 0.f, 0.f, 0.f);
    float4* o4 = reinterpret_cast<float4*>(out);
    for (int i = blk * 256 + t; i < OUT_FLOATS / 4; i += NBLK * 256)
      o4[i] = z;
  }

  const int g0  = half ? 28 : 0;    // first row-group of this half
  const int ng  = half ? 28 : 29;   // groups in this half
  const int nph = half ? 27 : 28;   // pooled rows in this half

  const float* img = x + (size_t)bc * (IH * IW);
  const float NEG = -3.4e38f;

  // stage 1: gm[g][wp] = max over rows 4g..4g+3, cols 4wp..4wp+7
  const int ncell = ng * 64;
  #pragma unroll 2
  for (int i = t; i < ncell; i += 256) {
    const int g  = g0 + (i >> 6);
    const int wp = i & 63;          // chunk index (chunks valid < 56)
    float cm = NEG;
    if (wp < 56) {
      const float* p0 = img + (4 * g) * IW + 4 * wp;
      float4 a0 = *reinterpret_cast<const float4*>(p0);
      float4 a1 = *reinterpret_cast<const float4*>(p0 + IW);
      float4 a2 = *reinterpret_cast<const float4*>(p0 + 2 * IW);
      float4 a3 = *reinterpret_cast<const float4*>(p0 + 3 * IW);
      float4 mm = max4(max4(a0, a1), max4(a2, a3));
      cm = fmaxf(fmaxf(mm.x, mm.y), fmaxf(mm.z, mm.w));
    }
    const float nb = __shfl_down(cm, 1);   // neighbor chunk (wp+1)
    gm[i] = fmaxf(cm, nb);                 // valid for wp < 55
  }
  __syncthreads();

  // stage 2: pooled[p][w] = max(gm[p], gm[p+1]) (relative rows); min/max
  float lmin = 3.4e38f, lmax = NEG;
  const int npc = nph * 64;
  for (int i = t; i < npc; i += 256) {
    const int hp = i >> 6;          // pooled row relative to this half
    const int w  = i & 63;
    if (w < PW) {
      float pm = fmaxf(gm[i], gm[i + 64]);
      lmin = fminf(lmin, pm);
      lmax = fmaxf(lmax, pm);
      if (c == 0 && half == 0 && hp < 3) poolv[b * 165 + hp * 55 + w] = pm;
    }
  }

  for (int off = 32; off > 0; off >>= 1) {
    lmin = fminf(lmin, __shfl_down(lmin, off));
    lmax = fmaxf(lmax, __shfl_down(lmax, off));
  }
  if ((t & 63) == 0) { rmin[t >> 6] = lmin; rmax[t >> 6] = lmax; }
  __syncthreads();
  if (t == 0) {
    partmin[blk] = fminf(fminf(rmin[0], rmin[1]), fminf(rmin[2], rmin[3]));
    partmax[blk] = fmaxf(fmaxf(rmax[0], rmax[1]), fmaxf(rmax[2], rmax[3]));
  }
}

// One thread per (b, m): compute the hash, store a single 1.0.
// d_out is already zeroed by pool_minmax_kernel.
__global__ __launch_bounds__(256) void encode_kernel(
    const int* __restrict__ R,
    const float* __restrict__ partmin,
    const float* __restrict__ partmax,
    const float* __restrict__ poolv,
    float* __restrict__ out)
{
  const int gid = blockIdx.x * 256 + threadIdx.x;
  const int b = gid >> 6;
  const int m = gid & 63;

  float xmin = partmin[b * 6], xmax = partmax[b * 6];
  #pragma unroll
  for (int i = 1; i < 6; ++i) {
    xmin = fminf(xmin, partmin[b * 6 + i]);
    xmax = fmaxf(xmax, partmax[b * 6 + i]);
  }
  const float denom = xmax - xmin + 1e-8f;   // same op order as reference

  int p = 0;
  #pragma unroll
  for (int k = 0; k < 8; ++k) {
    int idx = R[m * 8 + k] % 72600;          // n_elements = 3*55*55*8
    int f   = idx >> 3;                      // feature index (< 125 given R<1000)
    int l   = idx & 7;                       // threshold level
    float xn = (poolv[b * 165 + f] - xmin) / denom;
    if (xn > (float)(l + 1) * 0.125f) p += 128 >> k;   // weights 2^(7-k)
  }
  p &= 127;                                   // % VECTOR_SIZE (128)
  out[(size_t)b * 8192 + m * 128 + p] = 1.0f;
}

extern "C" void kernel_launch(void* const* d_in, const int* in_sizes, int n_in,
                              void* d_out, int out_size, void* d_ws, size_t ws_size,
                              hipStream_t stream) {
  const float* x   = (const float*)d_in[0];
  const int*   R   = (const int*)d_in[1];
  float*       out = (float*)d_out;

  float* partmin = (float*)d_ws;             // [1536]
  float* partmax = partmin + 1536;           // [1536]
  float* poolv   = partmax + 1536;           // [256 * 165]

  pool_minmax_kernel<<<NBLK, 256, 0, stream>>>(x, partmin, partmax, poolv, out);
  encode_kernel<<<64, 256, 0, stream>>>(R, partmin, partmax, poolv, out);
}

// Round 6
// 32.301 us; speedup vs baseline: 1.4008x; 1.0190x over previous
//
#include <hip/hip_runtime.h>

#define IH 224
#define IW 224
#define PH 55
#define PW 55
#define CH_CELLS (56 * 64)        // stage-1 cells (row-group x col-chunk) per channel
#define ALL_CELLS (3 * CH_CELLS)  // 10752
#define P_CELLS (55 * 64)         // stage-2 cells per channel
#define ALL_P (3 * P_CELLS)       // 10560

__device__ __forceinline__ float4 max4(float4 a, float4 b) {
  return make_float4(fmaxf(a.x, b.x), fmaxf(a.y, b.y),
                     fmaxf(a.z, b.z), fmaxf(a.w, b.w));
}

// One block per batch. Fully fused: zero own output row, stream all 3
// channels (each byte read once; window-8 via chunk max + __shfl_down),
// block-local min/max, 64-hash encode, scatter ones. No workspace, no
// atomics, no cross-block communication, single dispatch.
__global__ __launch_bounds__(1024, 4) void fused_kernel(
    const float* __restrict__ x,
    const int* __restrict__ R,
    float* __restrict__ out)
{
  __shared__ float gm[ALL_CELLS];   // 43 KB: per-(c,g) horizontal window maxes
  __shared__ int   sR[512];
  __shared__ float rmin[16], rmax[16];
  __shared__ float sMin, sMax;

  const int b = blockIdx.x;
  const int t = threadIdx.x;
  const float NEG = -3.4e38f;

  // prefetch R (512 ints) into LDS; consumed after later barriers
  if (t < 512) sR[t] = R[t];

  // zero this batch's output row (2048 float4, 2 per thread) — overlaps reads
  {
    float4* orow4 = reinterpret_cast<float4*>(out + (size_t)b * 8192);
    const float4 z = make_float4(0.f, 0.f, 0.f, 0.f);
    orow4[t] = z;
    orow4[t + 1024] = z;
  }

  const float* img = x + (size_t)b * (3 * IH * IW);

  // stage 1: gm[c][g][wp] = max over rows 4g..4g+3, cols 4wp..4wp+7
  for (int i = t; i < ALL_CELLS; i += 1024) {
    const int c  = i / CH_CELLS;
    const int r  = i - c * CH_CELLS;
    const int g  = r >> 6;
    const int wp = r & 63;          // chunk index (valid < 56)
    float cm = NEG;
    if (wp < 56) {
      const float* p0 = img + c * (IH * IW) + (4 * g) * IW + 4 * wp;
      float4 a0 = *reinterpret_cast<const float4*>(p0);
      float4 a1 = *reinterpret_cast<const float4*>(p0 + IW);
      float4 a2 = *reinterpret_cast<const float4*>(p0 + 2 * IW);
      float4 a3 = *reinterpret_cast<const float4*>(p0 + 3 * IW);
      float4 mm = max4(max4(a0, a1), max4(a2, a3));
      cm = fmaxf(fmaxf(mm.x, mm.y), fmaxf(mm.z, mm.w));
    }
    const float nb = __shfl_down(cm, 1);   // neighbor chunk (wp+1), same wave
    gm[i] = fmaxf(cm, nb);                 // valid for wp < 55
  }
  __syncthreads();

  // stage 2: pooled[c][hp][w] = max(gm[c][hp], gm[c][hp+1]); reduce min/max
  float lmin = 3.4e38f, lmax = NEG;
  for (int i = t; i < ALL_P; i += 1024) {
    const int c = i / P_CELLS;
    const int r = i - c * P_CELLS;
    const int w = r & 63;
    if (w < PW) {
      float pm = fmaxf(gm[c * CH_CELLS + r], gm[c * CH_CELLS + r + 64]);
      lmin = fminf(lmin, pm);
      lmax = fmaxf(lmax, pm);
    }
  }
  for (int off = 32; off > 0; off >>= 1) {
    lmin = fminf(lmin, __shfl_down(lmin, off));
    lmax = fmaxf(lmax, __shfl_down(lmax, off));
  }
  if ((t & 63) == 0) { rmin[t >> 6] = lmin; rmax[t >> 6] = lmax; }
  __syncthreads();
  if (t == 0) {
    float mn = rmin[0], mx = rmax[0];
    #pragma unroll
    for (int i = 1; i < 16; ++i) {
      mn = fminf(mn, rmin[i]);
      mx = fmaxf(mx, rmax[i]);
    }
    sMin = mn; sMax = mx;
  }
  __syncthreads();

  // encode: 64 hash positions, one 1.0 store each (row already zeroed above;
  // the intervening __syncthreads drain vmcnt, ordering stores)
  if (t < 64) {
    const float xmin  = sMin;
    const float denom = sMax - xmin + 1e-8f;   // same op order as reference
    int p = 0;
    #pragma unroll
    for (int k = 0; k < 8; ++k) {
      int idx = sR[t * 8 + k] % 72600;   // n_elements = 3*55*55*8
      int f   = idx >> 3;                // pooled feature index (general form)
      int l   = idx & 7;                 // threshold level
      int c   = f / 3025;
      int rem = f - c * 3025;
      int hp  = rem / 55;
      int w   = rem - hp * 55;
      float pm = fmaxf(gm[c * CH_CELLS + hp * 64 + w],
                       gm[c * CH_CELLS + hp * 64 + 64 + w]);
      float xn = (pm - xmin) / denom;
      if (xn > (float)(l + 1) * 0.125f) p += 128 >> k;   // weights 2^(7-k)
    }
    out[(size_t)b * 8192 + t * 128 + (p & 127)] = 1.0f;
  }
}

extern "C" void kernel_launch(void* const* d_in, const int* in_sizes, int n_in,
                              void* d_out, int out_size, void* d_ws, size_t ws_size,
                              hipStream_t stream) {
  const float* x   = (const float*)d_in[0];
  const int*   R   = (const int*)d_in[1];
  float*       out = (float*)d_out;

  fused_kernel<<<256, 1024, 0, stream>>>(x, R, out);
}